// Round 7
// baseline (340.642 us; speedup 1.0000x reference)
//
#include <hip/hip_runtime.h>
#include <hip/hip_bf16.h>
#include <cstdint>
#include <cstddef>

#define M_DIM 8192
#define K_DIM 4096
#define N_DIM 4096
#define EPS 1e-5f

typedef __bf16 bf16x8 __attribute__((ext_vector_type(8)));
typedef unsigned short u16x8 __attribute__((ext_vector_type(8)));
typedef float f32x4 __attribute__((ext_vector_type(4)));

// ---------- helpers ----------

__device__ __forceinline__ unsigned short f2bf(float f) {
  unsigned int u = __builtin_bit_cast(unsigned int, f);
  u += 0x7fffu + ((u >> 16) & 1u);   // round-to-nearest-even
  return (unsigned short)(u >> 16);
}

// GELU(tanh-approx)+ReLU via identity 0.5y(1+tanh(w)) = y*sigmoid(2w):
// ge = y / (1 + exp2(-c2*z)), z = y + 0.044715 y^3, c2 = 2*0.7978845608*log2(e)
__device__ __forceinline__ float fused_epilogue(float acc, float inv, float shift) {
  float y = fmaf(acc, inv, shift);
  float y2 = y * y;
  float z = fmaf(0.044715f * y2, y, y);
  float e = __builtin_amdgcn_exp2f(-2.3022081f * z);
  float ge = y * __builtin_amdgcn_rcpf(1.0f + e);
  return fmaxf(ge, 0.0f);
}

__device__ __forceinline__ void gload_lds16(const void* gsrc, void* ldst) {
  __builtin_amdgcn_global_load_lds(
      (const __attribute__((address_space(1))) void*)gsrc,
      (__attribute__((address_space(3))) void*)ldst,
      16, 0, 0);
}

// ---------- pre-pass: fp32 -> bf16 conversions ----------

__global__ __launch_bounds__(256) void cvt_x_kernel(const float* __restrict__ x,
                                                    unsigned short* __restrict__ xb) {
  size_t i = ((size_t)blockIdx.x * 256 + threadIdx.x) * 8;
  float4 a = *reinterpret_cast<const float4*>(x + i);
  float4 b = *reinterpret_cast<const float4*>(x + i + 4);
  u16x8 o;
  o[0] = f2bf(a.x); o[1] = f2bf(a.y); o[2] = f2bf(a.z); o[3] = f2bf(a.w);
  o[4] = f2bf(b.x); o[5] = f2bf(b.y); o[6] = f2bf(b.z); o[7] = f2bf(b.w);
  *reinterpret_cast<u16x8*>(xb + i) = o;
}

// W [K][N] fp32 -> Wt [N][K] bf16 (transpose + convert)
__global__ __launch_bounds__(256) void cvt_w_transpose(const float* __restrict__ W,
                                                       unsigned short* __restrict__ Wt) {
  __shared__ float tile[32][33];
  const int tx = threadIdx.x & 31;
  const int tg = threadIdx.x >> 5;
  const int n0 = blockIdx.x * 32;
  const int k0 = blockIdx.y * 32;
#pragma unroll
  for (int j = 0; j < 4; ++j) {
    int k = tg * 4 + j;
    tile[k][tx] = W[(size_t)(k0 + k) * N_DIM + n0 + tx];
  }
  __syncthreads();
#pragma unroll
  for (int j = 0; j < 4; ++j) {
    int n = tg * 4 + j;
    Wt[(size_t)(n0 + n) * K_DIM + k0 + tx] = f2bf(tile[tx][n]);
  }
}

// ---------- main GEMM: 128x256 tile, BK=32, 8 waves, 3-slot ring, 2 blocks/CU ----------
// A [M][K] bf16, Bt [N][K] bf16. Per-wave 64x64 out (acc=64 VGPR) so unified
// VGPR stays <=128 -> 4 waves/SIMD (2 co-resident blocks; cross-block overlap
// hides barrier/drain per m114). LDS ring: 3 slots x (A 4096 + B 8192 elems)
// = 72 KiB. Stage 2 tiles ahead; vmcnt(3) per tile (3 gloads/tile), never 0.
// Swizzle for [rows][32] layout: col8' = col8 ^ ((row>>2)&3) -> 2-way (free).

#define SLOT 12288

#define KT(T, SR, SW, ST, VM) do {                                                 \
  if (ST) {                                                                        \
    gload_lds16(aP + (size_t)((T) + 2) * 32, &lds[(SW)*SLOT + wv512]);             \
    gload_lds16(bP + (size_t)((T) + 2) * 32, &lds[(SW)*SLOT + 4096 + wv512]);      \
    gload_lds16(bP + 128 * (size_t)K_DIM + (size_t)((T) + 2) * 32,                 \
                &lds[(SW)*SLOT + 8192 + wv512]);                                   \
  }                                                                                \
  asm volatile("" ::: "memory");                                                   \
  bf16x8 aq[4], bq[4];                                                             \
  _Pragma("unroll") for (int ni = 0; ni < 4; ++ni)                                 \
    bq[ni] = __builtin_bit_cast(bf16x8,                                            \
        *(const u16x8*)&lds[(SR)*SLOT + bro + ni * 512]);                          \
  _Pragma("unroll") for (int mi = 0; mi < 4; ++mi)                                 \
    aq[mi] = __builtin_bit_cast(bf16x8,                                            \
        *(const u16x8*)&lds[(SR)*SLOT + aro + mi * 512]);                          \
  __builtin_amdgcn_s_setprio(1);                                                   \
  _Pragma("unroll") for (int mi = 0; mi < 4; ++mi)                                 \
  _Pragma("unroll") for (int ni = 0; ni < 4; ++ni)                                 \
    acc[mi][ni] = __builtin_amdgcn_mfma_f32_16x16x32_bf16(aq[mi], bq[ni],          \
                                                          acc[mi][ni], 0, 0, 0);   \
  __builtin_amdgcn_s_setprio(0);                                                   \
  if ((VM) >= 0) {                                                                 \
    asm volatile("s_waitcnt lgkmcnt(0)" ::: "memory");                             \
    if ((VM) == 3)      asm volatile("s_waitcnt vmcnt(3)" ::: "memory");           \
    else                asm volatile("s_waitcnt vmcnt(0)" ::: "memory");           \
    __builtin_amdgcn_s_barrier();                                                  \
  }                                                                                \
} while (0)

__global__ __launch_bounds__(512, 4) void gemm_bf16_fused(
    const unsigned short* __restrict__ A,
    const unsigned short* __restrict__ Bt,
    const float* __restrict__ gam, const float* __restrict__ bet,
    const float* __restrict__ mu, const float* __restrict__ var,
    float* __restrict__ C) {
  __shared__ __align__(16) unsigned short lds[36864];  // 72 KiB

  const int tid = threadIdx.x;
  const int wave = tid >> 6;
  const int lane = tid & 63;
  const int l15 = lane & 15, l4 = lane >> 4;
  const int wr = wave >> 2, wc = wave & 3;   // 2M x 4N wave grid; per-wave 64x64
  const int wv512 = wave * 512;

  // XCD-aware swizzle: 1024 blocks, 1024 % 8 == 0 -> bijective
  const int bid = (int)blockIdx.x;
  const int swz = (bid & 7) * 128 + (bid >> 3);
  const int bx = swz & 15;                   // 16 N-tiles (256 each)
  const int by = swz >> 4;                   // 64 M-tiles (128 each)
  const size_t bm = (size_t)by * 128;
  const size_t bn = (size_t)bx * 256;

  // stage source pointers (pre-swizzled per lane; gload-lds dest linear)
  const int srow = lane >> 2;                        // 0..15
  const int csrc = (lane & 3) ^ ((lane >> 4) & 3);   // inverse of store swizzle
  const unsigned short* aP = A  + (bm + (size_t)(wave * 16 + srow)) * K_DIM + csrc * 8;
  const unsigned short* bP = Bt + (bn + (size_t)(wave * 16 + srow)) * K_DIM + csrc * 8;

  // ds_read bases (elem units); col8' = l4 ^ (l15>>2)  (row>>2)&3 == l15>>2
  const int xk = (l4 ^ (l15 >> 2)) * 8;
  const int aro = (wr * 64 + l15) * 32 + xk;          // + mi*512
  const int bro = 4096 + (wc * 64 + l15) * 32 + xk;   // + ni*512

  f32x4 acc[4][4] = {};

  // ---- prologue: stage tile 0 -> slot0, tile 1 -> slot1 ----
  gload_lds16(aP,                          &lds[0 + wv512]);
  gload_lds16(bP,                          &lds[4096 + wv512]);
  gload_lds16(bP + 128 * (size_t)K_DIM,    &lds[8192 + wv512]);
  asm volatile("" ::: "memory");
  gload_lds16(aP + 32,                          &lds[SLOT + wv512]);
  gload_lds16(bP + 32,                          &lds[SLOT + 4096 + wv512]);
  gload_lds16(bP + 128 * (size_t)K_DIM + 32,    &lds[SLOT + 8192 + wv512]);
  asm volatile("s_waitcnt vmcnt(3)" ::: "memory");   // tile 0 landed
  __builtin_amdgcn_s_barrier();

  // ---- main loop: 128 K-tiles (BK=32), x3 unroll for ring slots ----
  for (int t = 0; t < 126; t += 3) {
    KT(t,     0, 2, 1, 3);
    KT(t + 1, 1, 0, 1, 3);
    KT(t + 2, 2, 1, 1, 3);
  }
  KT(126, 0, 0, 0, 0);    // no stage; drain tile 127's loads
  KT(127, 1, 0, 0, -1);   // last tile, no barrier

  // ---- epilogue: fused BN + GELU + ReLU ----
  const int row0 = (int)bm + wr * 64;
  const int col0 = (int)bn + wc * 64;
#pragma unroll
  for (int ni = 0; ni < 4; ++ni) {
    const int col = col0 + ni * 16 + l15;
    const float inv = rsqrtf(var[col] + EPS) * gam[col];
    const float shift = fmaf(-mu[col], inv, bet[col]);
#pragma unroll
    for (int mi = 0; mi < 4; ++mi) {
      const int r0 = row0 + mi * 16 + l4 * 4;
#pragma unroll
      for (int r = 0; r < 4; ++r)
        C[(size_t)(r0 + r) * N_DIM + col] = fused_epilogue(acc[mi][ni][r], inv, shift);
    }
  }
}

// ---------- fallback (only if ws too small): fp32 tiled GEMM ----------

__global__ __launch_bounds__(256) void gemm_f32_fallback(
    const float* __restrict__ A, const float* __restrict__ W,
    const float* __restrict__ gam, const float* __restrict__ bet,
    const float* __restrict__ mu, const float* __restrict__ var,
    float* __restrict__ C) {
  __shared__ float As[16][65];
  __shared__ float Bs[16][65];
  const int tid = threadIdx.x;
  const int tx = tid & 15, ty = tid >> 4;
  const int bn0 = blockIdx.x * 64, bm0 = blockIdx.y * 64;
  float acc[4][4] = {};
  for (int k0 = 0; k0 < K_DIM; k0 += 16) {
#pragma unroll
    for (int j = 0; j < 4; ++j)
      As[tid & 15][(tid >> 4) * 4 + j] =
          A[(size_t)(bm0 + (tid >> 4) * 4 + j) * K_DIM + k0 + (tid & 15)];
#pragma unroll
    for (int j = 0; j < 4; ++j)
      Bs[tid >> 4][(tid & 15) * 4 + j] =
          W[(size_t)(k0 + (tid >> 4)) * N_DIM + bn0 + (tid & 15) * 4 + j];
    __syncthreads();
#pragma unroll
    for (int kk = 0; kk < 16; ++kk) {
      float a_[4], b_[4];
#pragma unroll
      for (int i = 0; i < 4; ++i) a_[i] = As[kk][ty * 4 + i];
#pragma unroll
      for (int j = 0; j < 4; ++j) b_[j] = Bs[kk][tx * 4 + j];
#pragma unroll
      for (int i = 0; i < 4; ++i)
#pragma unroll
        for (int j = 0; j < 4; ++j)
          acc[i][j] = fmaf(a_[i], b_[j], acc[i][j]);
    }
    __syncthreads();
  }
#pragma unroll
  for (int j = 0; j < 4; ++j) {
    const int col = bn0 + tx * 4 + j;
    const float inv = rsqrtf(var[col] + EPS) * gam[col];
    const float shift = fmaf(-mu[col], inv, bet[col]);
#pragma unroll
    for (int i = 0; i < 4; ++i) {
      float y = fmaf(acc[i][j], inv, shift);
      float y2 = y * y;
      float z = fmaf(0.044715f * y2, y, y);
      float e = __builtin_amdgcn_exp2f(-2.3022081f * z);
      float ge = y * __builtin_amdgcn_rcpf(1.0f + e);
      C[(size_t)(bm0 + ty * 4 + i) * N_DIM + col] = fmaxf(ge, 0.0f);
    }
  }
}

// ---------- launch ----------

extern "C" void kernel_launch(void* const* d_in, const int* in_sizes, int n_in,
                              void* d_out, int out_size, void* d_ws, size_t ws_size,
                              hipStream_t stream) {
  const float* x  = (const float*)d_in[0];
  const float* w  = (const float*)d_in[1];
  const float* gg = (const float*)d_in[2];
  const float* bb = (const float*)d_in[3];
  const float* mu = (const float*)d_in[4];
  const float* vr = (const float*)d_in[5];
  float* out = (float*)d_out;

  const size_t xb_bytes = (size_t)M_DIM * K_DIM * 2;
  const size_t wt_bytes = (size_t)K_DIM * N_DIM * 2;

  if (ws_size >= xb_bytes + wt_bytes) {
    unsigned short* xb = (unsigned short*)d_ws;
    unsigned short* wt = xb + (size_t)M_DIM * K_DIM;
    cvt_x_kernel<<<dim3((M_DIM * (size_t)K_DIM) / 8 / 256), dim3(256), 0, stream>>>(x, xb);
    cvt_w_transpose<<<dim3(N_DIM / 32, K_DIM / 32), dim3(256), 0, stream>>>(w, wt);
    gemm_bf16_fused<<<dim3((M_DIM / 128) * (N_DIM / 256)), dim3(512), 0, stream>>>(
        xb, wt, gg, bb, mu, vr, out);
  } else {
    gemm_f32_fallback<<<dim3(N_DIM / 64, M_DIM / 64), dim3(256), 0, stream>>>(
        x, w, gg, bb, mu, vr, out);
  }
}